// Round 9
// baseline (24687.735 us; speedup 1.0000x reference)
//
#include <hip/hip_runtime.h>
#include <stdint.h>

#define T_STEPS 25
#define BB   4096
#define DIN  512
#define DH   1024
#define DOUT 256

struct Keys { uint32_t a[T_STEPS]; uint32_t b[T_STEPS]; };

// Threefry-2x32, exactly as JAX implements it (20 rounds, 5 groups of 4).
__host__ __device__ __forceinline__ void tf2x32(uint32_t k0, uint32_t k1,
                                                uint32_t x0, uint32_t x1,
                                                uint32_t& y0, uint32_t& y1) {
  const uint32_t ks2 = k0 ^ k1 ^ 0x1BD11BDAu;
  x0 += k0; x1 += k1;
#define TFR(r) { x0 += x1; x1 = (x1 << (r)) | (x1 >> (32 - (r))); x1 ^= x0; }
  TFR(13) TFR(15) TFR(26) TFR(6)   x0 += k1;  x1 += ks2 + 1u;
  TFR(17) TFR(29) TFR(16) TFR(24)  x0 += ks2; x1 += k0 + 2u;
  TFR(13) TFR(15) TFR(26) TFR(6)   x0 += k0;  x1 += k1 + 3u;
  TFR(17) TFR(29) TFR(16) TFR(24)  x0 += k1;  x1 += ks2 + 4u;
  TFR(13) TFR(15) TFR(26) TFR(6)   x0 += ks2; x1 += k0 + 5u;
#undef TFR
  y0 = x0; y1 = x1;
}

// Partitionable (modern JAX default) f32 bernoulli keep-bit (verified R5):
__device__ __forceinline__ bool keep_f(uint32_t ka, uint32_t kb, uint32_t e) {
  uint32_t y0, y1;
  tf2x32(ka, kb, 0u, e, y0, y1);
  return (((y0 ^ y1) >> 9) <= 6710886u);
}

// ---- LDS-tiled transpose: in [H][K] -> out [K][H]; H,K multiples of 32.
__global__ __launch_bounds__(256) void k_trt(const float* __restrict__ in,
                                             float* __restrict__ out, int H, int K) {
  __shared__ float tile[32][33];
  const int bh = blockIdx.x * 32, bk = blockIdx.y * 32;
  const int tx = threadIdx.x & 31, ty = threadIdx.x >> 5;   // 32 x 8
#pragma unroll
  for (int r = ty; r < 32; r += 8)
    tile[r][tx] = in[(size_t)(bh + r) * K + bk + tx];
  __syncthreads();
#pragma unroll
  for (int r = ty; r < 32; r += 8)
    out[(size_t)(bk + r) * H + bh + tx] = tile[tx][r];
}

// ---- cur1[b][h] = fma-chain_k(x[b,k]*w1[h,k]) + b1[h], ascending k, single acc.
__global__ __launch_bounds__(256) void k_cur1s(const float* __restrict__ xT,
                                               const float* __restrict__ w1t,
                                               const float* __restrict__ b1,
                                               float* __restrict__ cur1) {
  const int b  = blockIdx.x * 256 + threadIdx.x;
  const int h0 = blockIdx.y * 32;
  float acc[32];
#pragma unroll
  for (int i = 0; i < 32; ++i) acc[i] = 0.0f;
  for (int k = 0; k < DIN; ++k) {
    float xv = xT[(size_t)k * BB + b];                       // coalesced per-lane
    const float4* wk = (const float4*)(w1t + (size_t)k * DH + h0);  // wave-uniform
#pragma unroll
    for (int q = 0; q < 8; ++q) {
      float4 wv = wk[q];
      acc[q*4+0] = __fmaf_rn(xv, wv.x, acc[q*4+0]);
      acc[q*4+1] = __fmaf_rn(xv, wv.y, acc[q*4+1]);
      acc[q*4+2] = __fmaf_rn(xv, wv.z, acc[q*4+2]);
      acc[q*4+3] = __fmaf_rn(xv, wv.w, acc[q*4+3]);
    }
  }
  float* dst = cur1 + (size_t)b * DH + h0;
#pragma unroll
  for (int q = 0; q < 8; ++q) {
    float4 v;
    v.x = __fadd_rn(acc[q*4+0], b1[h0 + q*4 + 0]);
    v.y = __fadd_rn(acc[q*4+1], b1[h0 + q*4 + 1]);
    v.z = __fadd_rn(acc[q*4+2], b1[h0 + q*4 + 2]);
    v.w = __fadd_rn(acc[q*4+3], b1[h0 + q*4 + 3]);
    *(float4*)(dst + q*4) = v;
  }
}

// ---- all-25-steps mem1 trajectory (strict f32) + dropout -> bit masks along k.
__global__ __launch_bounds__(256) void k_trajf(const float* __restrict__ cur1,
                                               uint32_t* __restrict__ maskT, Keys kk) {
  const int e = blockIdx.x * 256 + threadIdx.x;    // e = b*1024 + h
  const int lane = threadIdx.x & 63;
  const int b = e >> 10;
  const int w = (e >> 5) & 31;
  const float c = cur1[e];
  float m = 0.0f;
  for (int t = 0; t < T_STEPS; ++t) {
    float r = (m > 1.0f) ? 1.0f : 0.0f;
    m = __fsub_rn(__fadd_rn(__fmul_rn(0.9f, m), c), r);
    bool spk = m > 1.0f;
    bool kp = keep_f(kk.a[t], kk.b[t], (uint32_t)e);
    unsigned long long ball = __ballot(spk && kp);
    if ((lane & 31) == 0)
      maskT[((size_t)t * 32 + w) * BB + b] = (uint32_t)(ball >> (lane & 32));
  }
}

// ---- batched GEMM, o-tile 32, lanes = rows, weights LDS-staged (double-buffered):
//      cur2[row][o] = fma-chain_k( sel(row,k) * w2t[k][o] ), ascending k.
// Weight chunk [32k][32o] = 4KB staged via T14 split (load-early/write-late);
// j-loop reads weights at wave-uniform LDS addresses (pure broadcast).
// sel in {0,1.25f} via bfe_i32+and (2 VALU). Chain bit-identical to reference.
__global__ __launch_bounds__(256) void k_gemm2(const uint32_t* __restrict__ maskT,
                                               const float* __restrict__ w2t,
                                               float* __restrict__ cur2) {
  __shared__ float wbuf[2][1024];
  const int tid = threadIdx.x;
  const int t  = blockIdx.x >> 4;                          // block-uniform
  const int b  = ((blockIdx.x & 15) << 8) + tid;           // row within t
  const int o0 = blockIdx.y * 32;
  const uint32_t* mrow = maskT + (size_t)t * 32 * BB + b;
  const float* wsrc = w2t + (size_t)(tid >> 3) * DOUT + o0 + ((tid & 7) << 2);

  // prologue: stage chunk 0, prefetch mask word 0
  *(float4*)&wbuf[0][tid * 4] = *(const float4*)(wsrc);
  uint32_t word = mrow[0];
  __syncthreads();

  float acc[32];
#pragma unroll
  for (int i = 0; i < 32; ++i) acc[i] = 0.0f;

  for (int w = 0; w < 32; ++w) {
    const int p = w & 1;
    float4 nxt;
    uint32_t wnxt = 0;
    if (w < 31) {                                          // issue-early (T14)
      nxt  = *(const float4*)(wsrc + (size_t)(w + 1) * 32 * DOUT);
      wnxt = mrow[(size_t)(w + 1) * BB];
    }
#pragma unroll
    for (int j = 0; j < 32; ++j) {
      int bm = ((int)(word << (31 - j))) >> 31;            // bfe_i32: 0 or -1
      float sel = __int_as_float(bm & 0x3FA00000);         // 0.0f or 1.25f
      const float* wp = &wbuf[p][j * 32];
#pragma unroll
      for (int q = 0; q < 8; ++q) {
        float4 wv = *(const float4*)(wp + q * 4);          // uniform addr: broadcast
        acc[q*4+0] = __fmaf_rn(sel, wv.x, acc[q*4+0]);
        acc[q*4+1] = __fmaf_rn(sel, wv.y, acc[q*4+1]);
        acc[q*4+2] = __fmaf_rn(sel, wv.z, acc[q*4+2]);
        acc[q*4+3] = __fmaf_rn(sel, wv.w, acc[q*4+3]);
      }
    }
    __syncthreads();                                       // all reads of wbuf done
    if (w < 31) *(float4*)&wbuf[p ^ 1][tid * 4] = nxt;     // write-late
    __syncthreads();
    word = wnxt;
  }

  float* dst = cur2 + ((size_t)t * BB + b) * DOUT + o0;
#pragma unroll
  for (int q = 0; q < 8; ++q)
    *(float4*)(dst + q*4) = make_float4(acc[q*4+0], acc[q*4+1], acc[q*4+2], acc[q*4+3]);
}

// ---- mem2 recursion (strict f32) + sigmoids. cur2 aliases out's second half.
__global__ __launch_bounds__(256) void k_out2(const float* __restrict__ b2,
                                              float* __restrict__ out) {
  const int b = blockIdx.x;
  const int o = threadIdx.x;
  float* out1 = out + (size_t)T_STEPS * BB * DOUT;   // == cur2 region
  const float bb = b2[o];
  float m = 0.0f;
  for (int t = 0; t < T_STEPS; ++t) {
    size_t p = ((size_t)t * BB + b) * DOUT + o;
    float c2 = __fadd_rn(out1[p], bb);
    float r = (m > 1.0f) ? 1.0f : 0.0f;
    m = __fsub_rn(__fadd_rn(__fmul_rn(0.9f, m), c2), r);
    out[p]  = (m > 1.0f) ? 0.7310585786300049f : 0.5f;
    out1[p] = 1.0f / (1.0f + __expf(-m));   // |delta| ~1e-5 << 0.0039 bf16 floor
  }
}

extern "C" void kernel_launch(void* const* d_in, const int* in_sizes, int n_in,
                              void* d_out, int out_size, void* d_ws, size_t ws_size,
                              hipStream_t stream) {
  const float* x  = (const float*)d_in[0];
  const float* w1 = (const float*)d_in[1];
  const float* b1 = (const float*)d_in[2];
  const float* w2 = (const float*)d_in[3];
  const float* b2 = (const float*)d_in[4];
  float* out = (float*)d_out;
  char* ws = (char*)d_ws;

  float*    w1t   = (float*)(ws);                   //  2 MB  [512][1024]
  float*    w2t   = (float*)(ws + 2097152);         //  1 MB  [1024][256]
  float*    xT    = (float*)(ws + 3145728);         //  8 MB  [512][4096]
  float*    cur1  = (float*)(ws + 11534336);        // 16 MB  [4096][1024]
  uint32_t* maskT = (uint32_t*)(ws + 28311552);     // 12.8MB [25][32][4096]
  float*    cur2  = out + (size_t)T_STEPS * BB * DOUT;  // reuse d_out 2nd half

  // partitionable (foldlike) split of key(42): key_t = threefry((0,42),(0,t))
  Keys kk;
  for (int t = 0; t < T_STEPS; ++t) {
    uint32_t y0, y1;
    tf2x32(0u, 42u, 0u, (uint32_t)t, y0, y1);
    kk.a[t] = y0; kk.b[t] = y1;
  }

  k_trt<<<dim3(DH / 32, DIN / 32), 256, 0, stream>>>(w1, w1t, DH, DIN);
  k_trt<<<dim3(DOUT / 32, DH / 32), 256, 0, stream>>>(w2, w2t, DOUT, DH);
  k_trt<<<dim3(BB / 32, DIN / 32), 256, 0, stream>>>(x, xT, BB, DIN);
  k_cur1s<<<dim3(BB / 256, DH / 32), 256, 0, stream>>>(xT, w1t, b1, cur1);
  k_trajf<<<dim3(BB * DH / 256), 256, 0, stream>>>(cur1, maskT, kk);
  k_gemm2<<<dim3(T_STEPS * 16, DOUT / 32), 256, 0, stream>>>(maskT, w2t, cur2);
  k_out2<<<dim3(BB), 256, 0, stream>>>(b2, out);
}

// Round 10
// 1521.083 us; speedup vs baseline: 16.2304x; 16.2304x over previous
//
#include <hip/hip_runtime.h>
#include <stdint.h>

#define T_STEPS 25
#define BB   4096
#define DIN  512
#define DH   1024
#define DOUT 256

struct Keys { uint32_t a[T_STEPS]; uint32_t b[T_STEPS]; };

// Threefry-2x32, exactly as JAX implements it (20 rounds, 5 groups of 4).
__host__ __device__ __forceinline__ void tf2x32(uint32_t k0, uint32_t k1,
                                                uint32_t x0, uint32_t x1,
                                                uint32_t& y0, uint32_t& y1) {
  const uint32_t ks2 = k0 ^ k1 ^ 0x1BD11BDAu;
  x0 += k0; x1 += k1;
#define TFR(r) { x0 += x1; x1 = (x1 << (r)) | (x1 >> (32 - (r))); x1 ^= x0; }
  TFR(13) TFR(15) TFR(26) TFR(6)   x0 += k1;  x1 += ks2 + 1u;
  TFR(17) TFR(29) TFR(16) TFR(24)  x0 += ks2; x1 += k0 + 2u;
  TFR(13) TFR(15) TFR(26) TFR(6)   x0 += k0;  x1 += k1 + 3u;
  TFR(17) TFR(29) TFR(16) TFR(24)  x0 += k1;  x1 += ks2 + 4u;
  TFR(13) TFR(15) TFR(26) TFR(6)   x0 += ks2; x1 += k0 + 5u;
#undef TFR
  y0 = x0; y1 = x1;
}

// Partitionable (modern JAX default) f32 bernoulli keep-bit (verified R5):
__device__ __forceinline__ bool keep_f(uint32_t ka, uint32_t kb, uint32_t e) {
  uint32_t y0, y1;
  tf2x32(ka, kb, 0u, e, y0, y1);
  return (((y0 ^ y1) >> 9) <= 6710886u);
}

// ---- LDS-tiled transpose: in [H][K] -> out [K][H]; H,K multiples of 32.
__global__ __launch_bounds__(256) void k_trt(const float* __restrict__ in,
                                             float* __restrict__ out, int H, int K) {
  __shared__ float tile[32][33];
  const int bh = blockIdx.x * 32, bk = blockIdx.y * 32;
  const int tx = threadIdx.x & 31, ty = threadIdx.x >> 5;   // 32 x 8
#pragma unroll
  for (int r = ty; r < 32; r += 8)
    tile[r][tx] = in[(size_t)(bh + r) * K + bk + tx];
  __syncthreads();
#pragma unroll
  for (int r = ty; r < 32; r += 8)
    out[(size_t)(bk + r) * H + bh + tx] = tile[tx][r];
}

// ---- cur1[b][h] = fma-chain_k(x[b,k]*w1[h,k]) + b1[h], ascending k, single acc.
__global__ __launch_bounds__(256) void k_cur1s(const float* __restrict__ xT,
                                               const float* __restrict__ w1t,
                                               const float* __restrict__ b1,
                                               float* __restrict__ cur1) {
  const int b  = blockIdx.x * 256 + threadIdx.x;
  const int h0 = blockIdx.y * 32;
  float acc[32];
#pragma unroll
  for (int i = 0; i < 32; ++i) acc[i] = 0.0f;
  for (int k = 0; k < DIN; ++k) {
    float xv = xT[(size_t)k * BB + b];                       // coalesced per-lane
    const float4* wk = (const float4*)(w1t + (size_t)k * DH + h0);  // wave-uniform
#pragma unroll
    for (int q = 0; q < 8; ++q) {
      float4 wv = wk[q];
      acc[q*4+0] = __fmaf_rn(xv, wv.x, acc[q*4+0]);
      acc[q*4+1] = __fmaf_rn(xv, wv.y, acc[q*4+1]);
      acc[q*4+2] = __fmaf_rn(xv, wv.z, acc[q*4+2]);
      acc[q*4+3] = __fmaf_rn(xv, wv.w, acc[q*4+3]);
    }
  }
  float* dst = cur1 + (size_t)b * DH + h0;
#pragma unroll
  for (int q = 0; q < 8; ++q) {
    float4 v;
    v.x = __fadd_rn(acc[q*4+0], b1[h0 + q*4 + 0]);
    v.y = __fadd_rn(acc[q*4+1], b1[h0 + q*4 + 1]);
    v.z = __fadd_rn(acc[q*4+2], b1[h0 + q*4 + 2]);
    v.w = __fadd_rn(acc[q*4+3], b1[h0 + q*4 + 3]);
    *(float4*)(dst + q*4) = v;
  }
}

// ---- all-25-steps mem1 trajectory (strict f32) + dropout -> bit masks along k.
__global__ __launch_bounds__(256) void k_trajf(const float* __restrict__ cur1,
                                               uint32_t* __restrict__ maskT, Keys kk) {
  const int e = blockIdx.x * 256 + threadIdx.x;    // e = b*1024 + h
  const int lane = threadIdx.x & 63;
  const int b = e >> 10;
  const int w = (e >> 5) & 31;
  const float c = cur1[e];
  float m = 0.0f;
  for (int t = 0; t < T_STEPS; ++t) {
    float r = (m > 1.0f) ? 1.0f : 0.0f;
    m = __fsub_rn(__fadd_rn(__fmul_rn(0.9f, m), c), r);
    bool spk = m > 1.0f;
    bool kp = keep_f(kk.a[t], kk.b[t], (uint32_t)e);
    unsigned long long ball = __ballot(spk && kp);
    if ((lane & 31) == 0)
      maskT[((size_t)t * 32 + w) * BB + b] = (uint32_t)(ball >> (lane & 32));
  }
}

// ---- batched GEMM, o-tile 32, lanes = rows; weights staged in LDS (single-buffer,
// two k-phases of 512), broadcast ds_read_b128 at wave-uniform addresses.
//      cur2[row][o] = fma-chain_k( sel(row,k) * w2t[k][o] ), ascending k.
// Anti-spill: fences every 2 j bound the hoistable ds_read window.
// sel in {0,1.25f} via bfe+and. Chain bit-identical to reference (R6-verified order).
__global__ __launch_bounds__(256) void k_gemm2(const uint32_t* __restrict__ maskT,
                                               const float* __restrict__ w2t,
                                               float* __restrict__ cur2) {
  __shared__ float wlds[512 * 36];                 // 72 KB, row stride 36 (16B-aligned)
  const int tid = threadIdx.x;
  const int t  = blockIdx.x >> 4;                  // block-uniform
  const int b  = ((blockIdx.x & 15) << 8) + tid;   // row within t
  const int o0 = blockIdx.y * 32;
  const uint32_t* mrow = maskT + (size_t)t * 32 * BB + b;

  float acc[32];
#pragma unroll
  for (int i = 0; i < 32; ++i) acc[i] = 0.0f;

  const int r0 = tid >> 3;                         // staging row base
  const int c4 = (tid & 7) << 2;                   // staging col (floats)

  uint32_t word = mrow[0];                         // pipeline head
  for (int phase = 0; phase < 2; ++phase) {
    __syncthreads();                               // prior phase's reads complete
#pragma unroll
    for (int i = 0; i < 16; ++i) {
      int r = r0 + i * 32;
      float4 v = *(const float4*)(w2t + (size_t)(phase * 512 + r) * DOUT + o0 + c4);
      *(float4*)&wlds[r * 36 + c4] = v;
    }
    __syncthreads();
    for (int w = 0; w < 16; ++w) {
      int wn = phase * 16 + w + 1; if (wn > 31) wn = 31;
      uint32_t wnext = mrow[(size_t)wn * BB];      // issue early, used next iter
      const float* wbase = &wlds[(w * 32) * 36];
#pragma unroll
      for (int j = 0; j < 32; ++j) {
        if ((j & 1) == 0) asm volatile("" ::: "memory");   // bound ds_read hoisting
        int bm = ((int)(word << (31 - j))) >> 31;          // bit j -> 0 / -1
        float sel = __int_as_float(bm & 0x3FA00000);       // 0.0f or 1.25f
        const float* wp = wbase + j * 36;
#pragma unroll
        for (int q = 0; q < 8; ++q) {
          float4 wv = *(const float4*)(wp + q * 4);        // uniform addr: broadcast
          acc[q*4+0] = __fmaf_rn(sel, wv.x, acc[q*4+0]);
          acc[q*4+1] = __fmaf_rn(sel, wv.y, acc[q*4+1]);
          acc[q*4+2] = __fmaf_rn(sel, wv.z, acc[q*4+2]);
          acc[q*4+3] = __fmaf_rn(sel, wv.w, acc[q*4+3]);
        }
      }
      word = wnext;
    }
  }

  float* dst = cur2 + ((size_t)t * BB + b) * DOUT + o0;
#pragma unroll
  for (int q = 0; q < 8; ++q)
    *(float4*)(dst + q*4) = make_float4(acc[q*4+0], acc[q*4+1], acc[q*4+2], acc[q*4+3]);
}

// ---- mem2 recursion (strict f32) + sigmoids. cur2 aliases out's second half.
__global__ __launch_bounds__(256) void k_out2(const float* __restrict__ b2,
                                              float* __restrict__ out) {
  const int b = blockIdx.x;
  const int o = threadIdx.x;
  float* out1 = out + (size_t)T_STEPS * BB * DOUT;   // == cur2 region
  const float bb = b2[o];
  float m = 0.0f;
  for (int t = 0; t < T_STEPS; ++t) {
    size_t p = ((size_t)t * BB + b) * DOUT + o;
    float c2 = __fadd_rn(out1[p], bb);
    float r = (m > 1.0f) ? 1.0f : 0.0f;
    m = __fsub_rn(__fadd_rn(__fmul_rn(0.9f, m), c2), r);
    out[p]  = (m > 1.0f) ? 0.7310585786300049f : 0.5f;
    out1[p] = 1.0f / (1.0f + __expf(-m));   // |delta| ~1e-5 << 0.0039 bf16 floor
  }
}

extern "C" void kernel_launch(void* const* d_in, const int* in_sizes, int n_in,
                              void* d_out, int out_size, void* d_ws, size_t ws_size,
                              hipStream_t stream) {
  const float* x  = (const float*)d_in[0];
  const float* w1 = (const float*)d_in[1];
  const float* b1 = (const float*)d_in[2];
  const float* w2 = (const float*)d_in[3];
  const float* b2 = (const float*)d_in[4];
  float* out = (float*)d_out;
  char* ws = (char*)d_ws;

  float*    w1t   = (float*)(ws);                   //  2 MB  [512][1024]
  float*    w2t   = (float*)(ws + 2097152);         //  1 MB  [1024][256]
  float*    xT    = (float*)(ws + 3145728);         //  8 MB  [512][4096]
  float*    cur1  = (float*)(ws + 11534336);        // 16 MB  [4096][1024]
  uint32_t* maskT = (uint32_t*)(ws + 28311552);     // 12.8MB [25][32][4096]
  float*    cur2  = out + (size_t)T_STEPS * BB * DOUT;  // reuse d_out 2nd half

  // partitionable (foldlike) split of key(42): key_t = threefry((0,42),(0,t))
  Keys kk;
  for (int t = 0; t < T_STEPS; ++t) {
    uint32_t y0, y1;
    tf2x32(0u, 42u, 0u, (uint32_t)t, y0, y1);
    kk.a[t] = y0; kk.b[t] = y1;
  }

  k_trt<<<dim3(DH / 32, DIN / 32), 256, 0, stream>>>(w1, w1t, DH, DIN);
  k_trt<<<dim3(DOUT / 32, DH / 32), 256, 0, stream>>>(w2, w2t, DOUT, DH);
  k_trt<<<dim3(BB / 32, DIN / 32), 256, 0, stream>>>(x, xT, BB, DIN);
  k_cur1s<<<dim3(BB / 256, DH / 32), 256, 0, stream>>>(xT, w1t, b1, cur1);
  k_trajf<<<dim3(BB * DH / 256), 256, 0, stream>>>(cur1, maskT, kk);
  k_gemm2<<<dim3(T_STEPS * 16, DOUT / 32), 256, 0, stream>>>(maskT, w2t, cur2);
  k_out2<<<dim3(BB), 256, 0, stream>>>(b2, out);
}

// Round 11
// 865.622 us; speedup vs baseline: 28.5202x; 1.7572x over previous
//
#include <hip/hip_runtime.h>
#include <stdint.h>

#define T_STEPS 25
#define BB   4096
#define DIN  512
#define DH   1024
#define DOUT 256

typedef float f32x2 __attribute__((ext_vector_type(2)));

struct Keys { uint32_t a[T_STEPS]; uint32_t b[T_STEPS]; };

// Threefry-2x32, exactly as JAX implements it (20 rounds, 5 groups of 4).
__host__ __device__ __forceinline__ void tf2x32(uint32_t k0, uint32_t k1,
                                                uint32_t x0, uint32_t x1,
                                                uint32_t& y0, uint32_t& y1) {
  const uint32_t ks2 = k0 ^ k1 ^ 0x1BD11BDAu;
  x0 += k0; x1 += k1;
#define TFR(r) { x0 += x1; x1 = (x1 << (r)) | (x1 >> (32 - (r))); x1 ^= x0; }
  TFR(13) TFR(15) TFR(26) TFR(6)   x0 += k1;  x1 += ks2 + 1u;
  TFR(17) TFR(29) TFR(16) TFR(24)  x0 += ks2; x1 += k0 + 2u;
  TFR(13) TFR(15) TFR(26) TFR(6)   x0 += k0;  x1 += k1 + 3u;
  TFR(17) TFR(29) TFR(16) TFR(24)  x0 += k1;  x1 += ks2 + 4u;
  TFR(13) TFR(15) TFR(26) TFR(6)   x0 += ks2; x1 += k0 + 5u;
#undef TFR
  y0 = x0; y1 = x1;
}

// Partitionable (modern JAX default) f32 bernoulli keep-bit (verified R5):
__device__ __forceinline__ bool keep_f(uint32_t ka, uint32_t kb, uint32_t e) {
  uint32_t y0, y1;
  tf2x32(ka, kb, 0u, e, y0, y1);
  return (((y0 ^ y1) >> 9) <= 6710886u);
}

// ---- LDS-tiled transpose: in [H][K] -> out [K][H]; H,K multiples of 32.
__global__ __launch_bounds__(256) void k_trt(const float* __restrict__ in,
                                             float* __restrict__ out, int H, int K) {
  __shared__ float tile[32][33];
  const int bh = blockIdx.x * 32, bk = blockIdx.y * 32;
  const int tx = threadIdx.x & 31, ty = threadIdx.x >> 5;   // 32 x 8
#pragma unroll
  for (int r = ty; r < 32; r += 8)
    tile[r][tx] = in[(size_t)(bh + r) * K + bk + tx];
  __syncthreads();
#pragma unroll
  for (int r = ty; r < 32; r += 8)
    out[(size_t)(bk + r) * H + bh + tx] = tile[tx][r];
}

// ---- cur1[b][h] = fma-chain_k(x[b,k]*w1[h,k]) + b1[h], ascending k, single acc.
// Packed f32x2 over h-pairs: chains stay per-h, same order -> bit-exact.
__global__ __launch_bounds__(256) void k_cur1s(const float* __restrict__ xT,
                                               const float* __restrict__ w1t,
                                               const float* __restrict__ b1,
                                               float* __restrict__ cur1) {
  const int b  = blockIdx.x * 256 + threadIdx.x;
  const int h0 = blockIdx.y * 32;
  f32x2 acc2[16];
#pragma unroll
  for (int i = 0; i < 16; ++i) acc2[i] = (f32x2){0.f, 0.f};
  for (int k = 0; k < DIN; ++k) {
    float xv = xT[(size_t)k * BB + b];                       // coalesced per-lane
    f32x2 xv2 = {xv, xv};
    const float4* wk = (const float4*)(w1t + (size_t)k * DH + h0);  // wave-uniform
#pragma unroll
    for (int q = 0; q < 8; ++q) {
      float4 wv = wk[q];
      f32x2 wlo = {wv.x, wv.y}, whi = {wv.z, wv.w};
      acc2[q*2+0] = __builtin_elementwise_fma(xv2, wlo, acc2[q*2+0]);
      acc2[q*2+1] = __builtin_elementwise_fma(xv2, whi, acc2[q*2+1]);
    }
  }
  float* dst = cur1 + (size_t)b * DH + h0;
#pragma unroll
  for (int i = 0; i < 16; ++i) {
    float2 v;
    v.x = __fadd_rn(acc2[i].x, b1[h0 + i*2 + 0]);
    v.y = __fadd_rn(acc2[i].y, b1[h0 + i*2 + 1]);
    *(float2*)(dst + i*2) = v;
  }
}

// ---- all-25-steps mem1 trajectory (strict f32) + dropout -> bit masks along k.
__global__ __launch_bounds__(256) void k_trajf(const float* __restrict__ cur1,
                                               uint32_t* __restrict__ maskT, Keys kk) {
  const int e = blockIdx.x * 256 + threadIdx.x;    // e = b*1024 + h
  const int lane = threadIdx.x & 63;
  const int b = e >> 10;
  const int w = (e >> 5) & 31;
  const float c = cur1[e];
  float m = 0.0f;
  for (int t = 0; t < T_STEPS; ++t) {
    float r = (m > 1.0f) ? 1.0f : 0.0f;
    m = __fsub_rn(__fadd_rn(__fmul_rn(0.9f, m), c), r);
    bool spk = m > 1.0f;
    bool kp = keep_f(kk.a[t], kk.b[t], (uint32_t)e);
    unsigned long long ball = __ballot(spk && kp);
    if ((lane & 31) == 0)
      maskT[((size_t)t * 32 + w) * BB + b] = (uint32_t)(ball >> (lane & 32));
  }
}

// ---- batched GEMM (R6 structure + packed f32), o-tile 32, lanes = rows:
//      cur2[row][o] = fma-chain_k( sel(row,k) * w2t[k][o] ), ascending k.
// Weights wave-uniform -> SGPR s_load (scalar pipe, off VALU/LDS).
// f32x2 packs column pairs: independent chains, same k order -> bit-exact.
__global__ __launch_bounds__(256) void k_gemm2(const uint32_t* __restrict__ maskT,
                                               const float* __restrict__ w2t,
                                               float* __restrict__ cur2) {
  const int row = blockIdx.x * 256 + threadIdx.x;  // flat t*4096+b; t block-uniform
  const int t = row >> 12, b = row & 4095;
  const int o0 = blockIdx.y * 32;
  const uint32_t* mrow = maskT + (size_t)t * 32 * BB + b;
  f32x2 acc2[16];
#pragma unroll
  for (int i = 0; i < 16; ++i) acc2[i] = (f32x2){0.f, 0.f};
  for (int w = 0; w < 32; ++w) {
    const uint32_t word = mrow[(size_t)w * BB];    // coalesced across lanes
    const float* wp = w2t + (size_t)(w * 32) * DOUT + o0;
#pragma unroll 2
    for (int j = 0; j < 32; ++j) {
      int bm = ((int)(word << (31 - j))) >> 31;            // bit j -> 0 / -1
      float sel = __int_as_float(bm & 0x3FA00000);         // 0.0f or 1.25f
      f32x2 sel2 = {sel, sel};
      const float4* wk = (const float4*)(wp + (size_t)j * DOUT);
#pragma unroll
      for (int q = 0; q < 8; ++q) {
        float4 wv = wk[q];
        f32x2 wlo = {wv.x, wv.y}, whi = {wv.z, wv.w};
        acc2[q*2+0] = __builtin_elementwise_fma(sel2, wlo, acc2[q*2+0]);
        acc2[q*2+1] = __builtin_elementwise_fma(sel2, whi, acc2[q*2+1]);
      }
    }
  }
  float* dst = cur2 + (size_t)row * DOUT + o0;
#pragma unroll
  for (int q = 0; q < 4; ++q) {
    float4 v0 = make_float4(acc2[q*4+0].x, acc2[q*4+0].y, acc2[q*4+1].x, acc2[q*4+1].y);
    float4 v1 = make_float4(acc2[q*4+2].x, acc2[q*4+2].y, acc2[q*4+3].x, acc2[q*4+3].y);
    *(float4*)(dst + q*8)     = v0;
    *(float4*)(dst + q*8 + 4) = v1;
  }
}

// ---- mem2 recursion (strict f32) + sigmoids. cur2 aliases out's second half.
__global__ __launch_bounds__(256) void k_out2(const float* __restrict__ b2,
                                              float* __restrict__ out) {
  const int b = blockIdx.x;
  const int o = threadIdx.x;
  float* out1 = out + (size_t)T_STEPS * BB * DOUT;   // == cur2 region
  const float bb = b2[o];
  float m = 0.0f;
  for (int t = 0; t < T_STEPS; ++t) {
    size_t p = ((size_t)t * BB + b) * DOUT + o;
    float c2 = __fadd_rn(out1[p], bb);
    float r = (m > 1.0f) ? 1.0f : 0.0f;
    m = __fsub_rn(__fadd_rn(__fmul_rn(0.9f, m), c2), r);
    out[p]  = (m > 1.0f) ? 0.7310585786300049f : 0.5f;
    out1[p] = 1.0f / (1.0f + __expf(-m));   // |delta| ~1e-5 << 0.0039 bf16 floor
  }
}

extern "C" void kernel_launch(void* const* d_in, const int* in_sizes, int n_in,
                              void* d_out, int out_size, void* d_ws, size_t ws_size,
                              hipStream_t stream) {
  const float* x  = (const float*)d_in[0];
  const float* w1 = (const float*)d_in[1];
  const float* b1 = (const float*)d_in[2];
  const float* w2 = (const float*)d_in[3];
  const float* b2 = (const float*)d_in[4];
  float* out = (float*)d_out;
  char* ws = (char*)d_ws;

  float*    w1t   = (float*)(ws);                   //  2 MB  [512][1024]
  float*    w2t   = (float*)(ws + 2097152);         //  1 MB  [1024][256]
  float*    xT    = (float*)(ws + 3145728);         //  8 MB  [512][4096]
  float*    cur1  = (float*)(ws + 11534336);        // 16 MB  [4096][1024]
  uint32_t* maskT = (uint32_t*)(ws + 28311552);     // 12.8MB [25][32][4096]
  float*    cur2  = out + (size_t)T_STEPS * BB * DOUT;  // reuse d_out 2nd half

  // partitionable (foldlike) split of key(42): key_t = threefry((0,42),(0,t))
  Keys kk;
  for (int t = 0; t < T_STEPS; ++t) {
    uint32_t y0, y1;
    tf2x32(0u, 42u, 0u, (uint32_t)t, y0, y1);
    kk.a[t] = y0; kk.b[t] = y1;
  }

  k_trt<<<dim3(DH / 32, DIN / 32), 256, 0, stream>>>(w1, w1t, DH, DIN);
  k_trt<<<dim3(DOUT / 32, DH / 32), 256, 0, stream>>>(w2, w2t, DOUT, DH);
  k_trt<<<dim3(BB / 32, DIN / 32), 256, 0, stream>>>(x, xT, BB, DIN);
  k_cur1s<<<dim3(BB / 256, DH / 32), 256, 0, stream>>>(xT, w1t, b1, cur1);
  k_trajf<<<dim3(BB * DH / 256), 256, 0, stream>>>(cur1, maskT, kk);
  k_gemm2<<<dim3(T_STEPS * BB / 256, DOUT / 32), 256, 0, stream>>>(maskT, w2t, cur2);
  k_out2<<<dim3(BB), 256, 0, stream>>>(b2, out);
}